// Round 13
// baseline (165.417 us; speedup 1.0000x reference)
//
#include <hip/hip_runtime.h>

#define BATCH 131072
#define XDIM 260          // 256 state + 4 goal
#define SDIM 256
#define HID 256
#define HHID 128
#define ODIM 128
#define NBLK 512          // k1 grid; 2 blocks/CU exactly
#define TILES 4           // 512 * 4 * 64 rows = 131072

typedef __attribute__((ext_vector_type(8))) short short8;     // raw 16B moves
typedef __attribute__((ext_vector_type(4))) short short4v;
typedef __attribute__((ext_vector_type(4))) float floatx4;    // MFMA accum
typedef __attribute__((ext_vector_type(8))) _Float16 half8;   // f16 MFMA frag

// fp32 -> fp16 RTNE. Proven absmax 9.77e-4 (R9-R12) vs 4.22e-3 threshold.
__device__ __forceinline__ short f2h(float f) {
    union { _Float16 h; short s; } u;
    u.h = (_Float16)f;
    return u.s;
}

// ---------------------------------------------------------------------------
// prep: weights -> fp16 in MFMA-fragment order (R11-proven).
//   W0F[c:16][kit:8][lane:64][e:8]   W1F[g][c:8][kit:8][lane][e]
//   W2F[g][c:8][kit:4][lane][e]
// frag value for lane (q=lane>>4, l15=lane&15), elem e:
//   W[k = kit*32 + q*8 + e][col = c*16 + l15]
// ---------------------------------------------------------------------------
__global__ void prep_kernel(const float* __restrict__ W0, const float* __restrict__ W1,
                            const float* __restrict__ W2, short* __restrict__ W0F,
                            short* __restrict__ W1F, short* __restrict__ W2F,
                            int* __restrict__ cursor) {
    int i = blockIdx.x * 256 + threadIdx.x;   // grid 512*256 = 131072
    if (i < 4) cursor[i] = 0;
    if (i < 65536) {            // W0F
        int e = i & 7, lane = (i >> 3) & 63, kit = (i >> 9) & 7, c = (i >> 12) & 15;
        int col = c * 16 + (lane & 15);
        int k = kit * 32 + (lane >> 4) * 8 + e;
        W0F[i] = f2h(W0[k * HID + col]);
    }
    {                           // W1F (exactly 131072 elements)
        int e = i & 7, lane = (i >> 3) & 63, kit = (i >> 9) & 7, c = (i >> 12) & 7, g = i >> 15;
        int col = c * 16 + (lane & 15);
        int k = kit * 32 + (lane >> 4) * 8 + e;
        W1F[i] = f2h(W1[(g * SDIM + k) * HHID + col]);
    }
    if (i < 65536) {            // W2F
        int e = i & 7, lane = (i >> 3) & 63, kit = (i >> 9) & 3, c = (i >> 11) & 7, g = i >> 14;
        int col = c * 16 + (lane & 15);
        int k = kit * 32 + (lane >> 4) * 8 + e;
        W2F[i] = f2h(W2[(g * HHID + k) * ODIM + col]);
    }
}

// ---------------------------------------------------------------------------
// bucket: per-row argmax(goal) -> counting sort (hierarchical; R2-proven).
// ---------------------------------------------------------------------------
__global__ void bucket_kernel(const float* __restrict__ x, int* __restrict__ cursor,
                              int* __restrict__ perm) {
    __shared__ int lhist[4];
    __shared__ int lbase[4];
    const int tid = threadIdx.x;
    if (tid < 4) lhist[tid] = 0;
    __syncthreads();

    const int row = blockIdx.x * 256 + tid;
    const float4 gv = *reinterpret_cast<const float4*>(x + (size_t)row * XDIM + SDIM);
    int gi = 0; float best = gv.x;
    if (gv.y > best) { best = gv.y; gi = 1; }   // strict > keeps first max (jnp.argmax)
    if (gv.z > best) { best = gv.z; gi = 2; }
    if (gv.w > best) { best = gv.w; gi = 3; }

    const int lpos = atomicAdd(&lhist[gi], 1);
    __syncthreads();
    if (tid < 4) lbase[tid] = atomicAdd(&cursor[tid], lhist[tid]);
    __syncthreads();
    perm[gi * BATCH + lbase[gi] + lpos] = row;
}

// ---------------------------------------------------------------------------
// K1: h = LeakyReLU(LN(state @ W0 + b0)) -> fp16 H (aliases d_out, in place).
// R13 delta: grid-stride (512 blocks x 4 tiles) with double-buffered LDS +
// register prefetch (T14 async-STAGE). Per-tile instruction sequence
// (staging convert, GEMM kit order, LN tree, scalar h store) is IDENTICAL
// to R11 -> bit-identical output. While GEMM(t) reads buf[t&1], tile t+1
// (in regs since last iter) is written to buf[t&1^1] and tile t+2's loads
// are issued -> HBM fetch stays busy under compute (fixes the ~20% fetch
// duty cycle that capped k1 at 1.7 TB/s).
// ---------------------------------------------------------------------------
__global__ __launch_bounds__(256, 2) void k1_gemm_ln(
        const float* __restrict__ x, const float* __restrict__ b0,
        const float* __restrict__ gamma, const float* __restrict__ beta,
        const short* __restrict__ W0F, short* __restrict__ H) {
    __shared__ __align__(16) short a_lds[2][64][264];   // 67.6 KB double buffer
    __shared__ float psum[64][4];
    __shared__ float psq[64][4];
    __shared__ float mu_s[64];
    __shared__ float rs_s[64];

    const int tid = threadIdx.x;
    const int lane = tid & 63;
    const int w = tid >> 6;
    const int q = lane >> 4;
    const int l15 = lane & 15;

    const short8* B0 = reinterpret_cast<const short8*>(W0F) + (w << 11) + lane;

    // ---- prologue: stage tile blockIdx.x into buf0 (R11-proven pattern)
    {
        const int m0 = blockIdx.x * 64;
        #pragma unroll
        for (int half = 0; half < 2; ++half) {
            float4 v[8];
            #pragma unroll
            for (int c = 0; c < 8; ++c) {
                int s = (half * 8 + c) * 256 + tid;
                int row = s >> 6;
                int k4 = (s & 63) << 2;
                v[c] = *reinterpret_cast<const float4*>(x + (size_t)(m0 + row) * XDIM + k4);
            }
            __builtin_amdgcn_sched_barrier(0);
            #pragma unroll
            for (int c = 0; c < 8; ++c) {
                int s = (half * 8 + c) * 256 + tid;
                int row = s >> 6;
                int k4 = (s & 63) << 2;
                short4v sv;
                sv.x = f2h(v[c].x); sv.y = f2h(v[c].y); sv.z = f2h(v[c].z); sv.w = f2h(v[c].w);
                *reinterpret_cast<short4v*>(&a_lds[0][row][k4]) = sv;
            }
        }
    }

    // ---- issue prefetch loads for tile blockIdx.x + NBLK
    float4 vp[16];
    {
        const int m1 = (blockIdx.x + NBLK) * 64;
        #pragma unroll
        for (int c = 0; c < 16; ++c) {
            int s = c * 256 + tid;
            int row = s >> 6;
            int k4 = (s & 63) << 2;
            vp[c] = *reinterpret_cast<const float4*>(x + (size_t)(m1 + row) * XDIM + k4);
        }
        __builtin_amdgcn_sched_barrier(0);
    }

    for (int t = 0; t < TILES; ++t) {
        const int cur = t & 1;
        const int m0 = (blockIdx.x + t * NBLK) * 64;
        __syncthreads();   // buf[cur] staged; all prior reads of buf[cur^1] done

        // ---- GEMM: 64x256, K=256; wave w owns cols [w*64, w*64+64)
        floatx4 acc[4][4] = {};   // rows mi*16+q*4+r, cols w*64+ni*16+l15
        #pragma unroll
        for (int kit = 0; kit < 8; ++kit) {
            half8 af[4], bf[4];
            #pragma unroll
            for (int mi = 0; mi < 4; ++mi)
                af[mi] = *reinterpret_cast<const half8*>(&a_lds[cur][mi * 16 + l15][kit * 32 + q * 8]);
            #pragma unroll
            for (int ni = 0; ni < 4; ++ni)
                bf[ni] = *reinterpret_cast<const half8*>(&B0[(ni << 9) + (kit << 6)]);
            #pragma unroll
            for (int mi = 0; mi < 4; ++mi)
                #pragma unroll
                for (int ni = 0; ni < 4; ++ni)
                    acc[mi][ni] = __builtin_amdgcn_mfma_f32_16x16x32_f16(af[mi], bf[ni], acc[mi][ni], 0, 0, 0);
        }

        // ---- overlap zone: land tile t+1 into buf[cur^1]; issue tile t+2
        if (t < TILES - 1) {
            #pragma unroll
            for (int c = 0; c < 16; ++c) {
                int s = c * 256 + tid;
                int row = s >> 6;
                int k4 = (s & 63) << 2;
                short4v sv;
                sv.x = f2h(vp[c].x); sv.y = f2h(vp[c].y); sv.z = f2h(vp[c].z); sv.w = f2h(vp[c].w);
                *reinterpret_cast<short4v*>(&a_lds[cur ^ 1][row][k4]) = sv;
            }
            if (t < TILES - 2) {
                const int mn = (blockIdx.x + (t + 2) * NBLK) * 64;
                #pragma unroll
                for (int c = 0; c < 16; ++c) {
                    int s = c * 256 + tid;
                    int row = s >> 6;
                    int k4 = (s & 63) << 2;
                    vp[c] = *reinterpret_cast<const float4*>(x + (size_t)(mn + row) * XDIM + k4);
                }
                __builtin_amdgcn_sched_barrier(0);
            }
        }

        // ---- + b0, LN stats (R2-proven serial-shfl reduction)
        float bias[4], gm[4], bt[4];
        #pragma unroll
        for (int ni = 0; ni < 4; ++ni) {
            int col = (w << 6) + ni * 16 + l15;
            bias[ni] = b0[col]; gm[ni] = gamma[col]; bt[ni] = beta[col];
        }
        #pragma unroll
        for (int mi = 0; mi < 4; ++mi) {
            #pragma unroll
            for (int r = 0; r < 4; ++r) {
                float s = 0.f, ss = 0.f;
                #pragma unroll
                for (int ni = 0; ni < 4; ++ni) {
                    float v = acc[mi][ni][r] + bias[ni];
                    acc[mi][ni][r] = v;
                    s += v; ss += v * v;
                }
                #pragma unroll
                for (int off = 1; off < 16; off <<= 1) {
                    s  += __shfl_xor(s,  off, 64);
                    ss += __shfl_xor(ss, off, 64);
                }
                if (l15 == 0) {
                    int row = mi * 16 + q * 4 + r;
                    psum[row][w] = s;
                    psq[row][w]  = ss;
                }
            }
        }
        __syncthreads();
        if (tid < 64) {
            float s  = psum[tid][0] + psum[tid][1] + psum[tid][2] + psum[tid][3];
            float ss = psq[tid][0]  + psq[tid][1]  + psq[tid][2]  + psq[tid][3];
            float mu = s * (1.f / 256.f);
            float var = ss * (1.f / 256.f) - mu * mu;
            mu_s[tid] = mu;
            rs_s[tid] = rsqrtf(var + 1e-5f);
        }
        __syncthreads();

        // ---- normalize + leaky + store fp16 (R2-proven scalar store epilogue)
        #pragma unroll
        for (int mi = 0; mi < 4; ++mi) {
            #pragma unroll
            for (int r = 0; r < 4; ++r) {
                int row = mi * 16 + q * 4 + r;
                float mu = mu_s[row], rs = rs_s[row];
                short* dst = H + (size_t)(m0 + row) * HID + (w << 6) + l15;
                #pragma unroll
                for (int ni = 0; ni < 4; ++ni) {
                    float v = (acc[mi][ni][r] - mu) * rs * gm[ni] + bt[ni];
                    v = (v >= 0.f) ? v : 0.1f * v;
                    dst[ni * 16] = f2h(v);
                }
            }
        }
    }
}

// ---------------------------------------------------------------------------
// K2: per (goal g, 64-row tile): t = relu(h @ W1[g] + b1[g]); out = t @ W2[g] + b2[g]
// H aliases out row-in-place (R2-proven race-free). R11-proven; untouched.
// ---------------------------------------------------------------------------
__global__ __launch_bounds__(256, 2) void k2_heads(
        const short* H, const short* __restrict__ W1F, const short* __restrict__ W2F,
        const float* __restrict__ b1, const float* __restrict__ b2,
        const int* __restrict__ cursor, const int* __restrict__ perm,
        float* out) {
    const int g = blockIdx.y;
    const int t = blockIdx.x;
    const int cnt = cursor[g];
    if (t * 64 >= cnt) return;

    __shared__ __align__(16) short a_lds[64][264];
    __shared__ __align__(16) short t_lds[64][136];
    __shared__ int rows_s[64];

    const int tid = threadIdx.x;
    const int lane = tid & 63;
    const int w = tid >> 6;
    const int* pg = perm + (size_t)g * BATCH;

    if (tid < 64) {
        int idx = t * 64 + tid;
        rows_s[tid] = pg[idx < cnt ? idx : cnt - 1];
    }
    __syncthreads();

    // ---- gather h rows (fp16), coalesced 16B/lane
    #pragma unroll
    for (int c = 0; c < 8; ++c) {
        int s = c * 256 + tid;                 // 16B slot, 64 rows x 32 slots
        int row = s >> 5;
        int k8 = (s & 31) << 3;
        short8 v = *reinterpret_cast<const short8*>(H + (size_t)rows_s[row] * HID + k8);
        *reinterpret_cast<short8*>(&a_lds[row][k8]) = v;
    }
    __syncthreads();

    const int q = lane >> 4;
    const int l15 = lane & 15;

    // ---- GEMM1: 64x128, K=256; wave w owns cols [w*32, w*32+32)
    floatx4 acc1[4][2] = {};
    const short8* B1 = reinterpret_cast<const short8*>(W1F) + (g << 12) + (w << 10) + lane;
    #pragma unroll
    for (int kit = 0; kit < 8; ++kit) {
        half8 af[4], bf[2];
        #pragma unroll
        for (int mi = 0; mi < 4; ++mi)
            af[mi] = *reinterpret_cast<const half8*>(&a_lds[mi * 16 + l15][kit * 32 + q * 8]);
        #pragma unroll
        for (int ni = 0; ni < 2; ++ni)
            bf[ni] = *reinterpret_cast<const half8*>(&B1[(ni << 9) + (kit << 6)]);
        #pragma unroll
        for (int mi = 0; mi < 4; ++mi)
            #pragma unroll
            for (int ni = 0; ni < 2; ++ni)
                acc1[mi][ni] = __builtin_amdgcn_mfma_f32_16x16x32_f16(af[mi], bf[ni], acc1[mi][ni], 0, 0, 0);
    }
    // bias + relu -> t_lds (fp16)
    #pragma unroll
    for (int ni = 0; ni < 2; ++ni) {
        int col = (w << 5) + ni * 16 + l15;
        float bb = b1[g * HHID + col];
        #pragma unroll
        for (int mi = 0; mi < 4; ++mi)
            #pragma unroll
            for (int r = 0; r < 4; ++r) {
                int row = mi * 16 + q * 4 + r;
                float v = acc1[mi][ni][r] + bb;
                t_lds[row][col] = f2h(v > 0.f ? v : 0.f);
            }
    }
    __syncthreads();

    // ---- GEMM2: 64x128, K=128
    floatx4 acc2[4][2] = {};
    const short8* B2 = reinterpret_cast<const short8*>(W2F) + (g << 11) + (w << 9) + lane;
    #pragma unroll
    for (int kit = 0; kit < 4; ++kit) {
        half8 af[4], bf[2];
        #pragma unroll
        for (int mi = 0; mi < 4; ++mi)
            af[mi] = *reinterpret_cast<const half8*>(&t_lds[mi * 16 + l15][kit * 32 + q * 8]);
        #pragma unroll
        for (int ni = 0; ni < 2; ++ni)
            bf[ni] = *reinterpret_cast<const half8*>(&B2[(ni << 8) + (kit << 6)]);
        #pragma unroll
        for (int mi = 0; mi < 4; ++mi)
            #pragma unroll
            for (int ni = 0; ni < 2; ++ni)
                acc2[mi][ni] = __builtin_amdgcn_mfma_f32_16x16x32_f16(af[mi], bf[ni], acc2[mi][ni], 0, 0, 0);
    }
    // bias + scatter out (fp32)
    #pragma unroll
    for (int ni = 0; ni < 2; ++ni) {
        int col = (w << 5) + ni * 16 + l15;
        float bb = b2[g * ODIM + col];
        #pragma unroll
        for (int mi = 0; mi < 4; ++mi)
            #pragma unroll
            for (int r = 0; r < 4; ++r) {
                int row = mi * 16 + q * 4 + r;
                int idx = t * 64 + row;
                if (idx < cnt)
                    out[(size_t)rows_s[row] * ODIM + col] = acc2[mi][ni][r] + bb;
            }
    }
}

// ---------------------------------------------------------------------------
// workspace layout (2.62 MB):
//   [0, 131072)            W0F fp16 (fragment-ordered)
//   [131072, 393216)       W1F fp16
//   [393216, 524288)       W2F fp16
//   [524288, 524304)       cursor (padded to 1024)
//   [525312, 2622464)      perm (4 x 131072 int)
// h (fp16, 64 MB) lives in d_out (row-in-place; one owner block per row).
// ---------------------------------------------------------------------------
extern "C" void kernel_launch(void* const* d_in, const int* in_sizes, int n_in,
                              void* d_out, int out_size, void* d_ws, size_t ws_size,
                              hipStream_t stream) {
    const float* x     = (const float*)d_in[0];
    const float* W0    = (const float*)d_in[1];
    const float* b0    = (const float*)d_in[2];
    const float* gamma = (const float*)d_in[3];
    const float* beta  = (const float*)d_in[4];
    const float* W1    = (const float*)d_in[5];
    const float* b1    = (const float*)d_in[6];
    const float* W2    = (const float*)d_in[7];
    const float* b2    = (const float*)d_in[8];

    char* ws = (char*)d_ws;
    short* W0F  = (short*)(ws);
    short* W1F  = (short*)(ws + 131072);
    short* W2F  = (short*)(ws + 393216);
    int* cursor = (int*)(ws + 524288);
    int* perm   = (int*)(ws + 525312);
    short* H    = (short*)d_out;           // fp16 h aliases the fp32 output buffer
    float* out  = (float*)d_out;

    prep_kernel<<<512, 256, 0, stream>>>(W0, W1, W2, W0F, W1F, W2F, cursor);
    bucket_kernel<<<512, 256, 0, stream>>>(x, cursor, perm);
    k1_gemm_ln<<<NBLK, 256, 0, stream>>>(x, b0, gamma, beta, W0F, H);
    k2_heads<<<dim3(BATCH / 64, 4), 256, 0, stream>>>(H, W1F, W2F, b1, b2, cursor, perm, out);
}

// Round 14
// 135.108 us; speedup vs baseline: 1.2243x; 1.2243x over previous
//
#include <hip/hip_runtime.h>

#define BATCH 131072
#define XDIM 260          // 256 state + 4 goal
#define SDIM 256
#define HID 256
#define HHID 128
#define ODIM 128

typedef __attribute__((ext_vector_type(8))) short short8;     // raw 16B moves
typedef __attribute__((ext_vector_type(4))) float floatx4;    // MFMA accum
typedef __attribute__((ext_vector_type(8))) _Float16 half8;   // f16 MFMA frag

// fp32 -> fp16 RTNE. Proven absmax 9.77e-4 (R9-R12) vs 4.22e-3 threshold.
__device__ __forceinline__ short f2h(float f) {
    union { _Float16 h; short s; } u;
    u.h = (_Float16)f;
    return u.s;
}

// ---------------------------------------------------------------------------
// prep: weights -> fp16 in MFMA-fragment order (R11-proven, untouched).
//   W0F[c:16][kit:8][lane:64][e:8]   W1F[g][c:8][kit:8][lane][e]
//   W2F[g][c:8][kit:4][lane][e]
// frag value for lane (q=lane>>4, l15=lane&15), elem e:
//   W[k = kit*32 + q*8 + e][col = c*16 + l15]
// ---------------------------------------------------------------------------
__global__ void prep_kernel(const float* __restrict__ W0, const float* __restrict__ W1,
                            const float* __restrict__ W2, short* __restrict__ W0F,
                            short* __restrict__ W1F, short* __restrict__ W2F,
                            int* __restrict__ cursor) {
    int i = blockIdx.x * 256 + threadIdx.x;   // grid 512*256 = 131072
    if (i < 4) cursor[i] = 0;
    if (i < 65536) {            // W0F
        int e = i & 7, lane = (i >> 3) & 63, kit = (i >> 9) & 7, c = (i >> 12) & 15;
        int col = c * 16 + (lane & 15);
        int k = kit * 32 + (lane >> 4) * 8 + e;
        W0F[i] = f2h(W0[k * HID + col]);
    }
    {                           // W1F (exactly 131072 elements)
        int e = i & 7, lane = (i >> 3) & 63, kit = (i >> 9) & 7, c = (i >> 12) & 7, g = i >> 15;
        int col = c * 16 + (lane & 15);
        int k = kit * 32 + (lane >> 4) * 8 + e;
        W1F[i] = f2h(W1[(g * SDIM + k) * HHID + col]);
    }
    if (i < 65536) {            // W2F
        int e = i & 7, lane = (i >> 3) & 63, kit = (i >> 9) & 3, c = (i >> 11) & 7, g = i >> 14;
        int col = c * 16 + (lane & 15);
        int k = kit * 32 + (lane >> 4) * 8 + e;
        W2F[i] = f2h(W2[(g * HHID + k) * ODIM + col]);
    }
}

// ---------------------------------------------------------------------------
// bucket: per-row argmax(goal) -> counting sort (hierarchical; R2-proven).
// ---------------------------------------------------------------------------
__global__ void bucket_kernel(const float* __restrict__ x, int* __restrict__ cursor,
                              int* __restrict__ perm) {
    __shared__ int lhist[4];
    __shared__ int lbase[4];
    const int tid = threadIdx.x;
    if (tid < 4) lhist[tid] = 0;
    __syncthreads();

    const int row = blockIdx.x * 256 + tid;
    const float4 gv = *reinterpret_cast<const float4*>(x + (size_t)row * XDIM + SDIM);
    int gi = 0; float best = gv.x;
    if (gv.y > best) { best = gv.y; gi = 1; }   // strict > keeps first max (jnp.argmax)
    if (gv.z > best) { best = gv.z; gi = 2; }
    if (gv.w > best) { best = gv.w; gi = 3; }

    const int lpos = atomicAdd(&lhist[gi], 1);
    __syncthreads();
    if (tid < 4) lbase[tid] = atomicAdd(&cursor[tid], lhist[tid]);
    __syncthreads();
    perm[gi * BATCH + lbase[gi] + lpos] = row;
}

// ---------------------------------------------------------------------------
// xcvt: x(state) fp32 -> XB fp16 in per-tile A-FRAGMENT order (XB aliases
// d_out). R14's one mechanism: apply R11's fragment-ordering win (B operand,
// +16us) to the A operand, paid for once in a streaming pass. Chunk (r,c)
// [r=row-in-tile, c=16B col chunk] lands at tile*2048 + kit*256+mi*64+q*16+l15
// (16B units) where kit=c>>2, q=c&3, mi=r>>4, l15=r&15 -- so k1's af[mi] load
// is one contiguous 1KB wave load. Reads fully coalesced (32B/thread).
// ---------------------------------------------------------------------------
__global__ void xcvt_kernel(const float* __restrict__ x, short* __restrict__ XB) {
    const int tid = threadIdx.x;
    const int tile = blockIdx.x;
    const int m0 = tile * 64;
    short8* X8 = reinterpret_cast<short8*>(XB) + ((size_t)tile << 11);
    #pragma unroll
    for (int i = 0; i < 8; ++i) {
        int s = i * 256 + tid;          // 2048 chunks: r = s>>5, c = s&31
        int r = s >> 5;
        int c = s & 31;
        const float* xr = x + (size_t)(m0 + r) * XDIM + c * 8;
        float4 a = *reinterpret_cast<const float4*>(xr);
        float4 b = *reinterpret_cast<const float4*>(xr + 4);
        short8 sv;
        sv[0] = f2h(a.x); sv[1] = f2h(a.y); sv[2] = f2h(a.z); sv[3] = f2h(a.w);
        sv[4] = f2h(b.x); sv[5] = f2h(b.y); sv[6] = f2h(b.z); sv[7] = f2h(b.w);
        int kit = c >> 2, q = c & 3, mi = r >> 4, l15 = r & 15;
        X8[(kit << 8) + (mi << 6) + (q << 4) + l15] = sv;
    }
}

// ---------------------------------------------------------------------------
// K1d: h = LeakyReLU(LN(A @ W0 + b0)) -> fp16 H, in place over its own XB
// tile. NO LDS STAGING: A-frags are contiguous 1KB wave loads from
// fragment-ordered XB (L3-resident, written by xcvt). LDS = 2.3KB (LN only).
// GEMM consumes identical f2h values in identical lanes/order as R11; LN and
// store are byte-frozen R11 -> bit-identical output.
// In-place safety: all A-loads complete (consumed by MFMA) before the LN
// __syncthreads(); all h-stores happen after it.
// ---------------------------------------------------------------------------
__global__ __launch_bounds__(256, 4) void k1d_gemm_ln(
        const short* XB, const float* __restrict__ b0,
        const float* __restrict__ gamma, const float* __restrict__ beta,
        const short* __restrict__ W0F, short* H) {
    __shared__ float psum[64][4];
    __shared__ float psq[64][4];
    __shared__ float mu_s[64];
    __shared__ float rs_s[64];

    const int tid = threadIdx.x;
    const int lane = tid & 63;
    const int w = tid >> 6;
    const int q = lane >> 4;
    const int l15 = lane & 15;
    const int tile = blockIdx.x;
    const int m0 = tile * 64;

    const short8* A0 = reinterpret_cast<const short8*>(XB) + ((size_t)tile << 11);
    const short8* B0 = reinterpret_cast<const short8*>(W0F) + (w << 11) + lane;

    floatx4 acc[4][4] = {};   // rows mi*16+q*4+r, cols w*64+ni*16+l15
    #pragma unroll
    for (int kit = 0; kit < 8; ++kit) {
        half8 af[4], bf[4];
        #pragma unroll
        for (int mi = 0; mi < 4; ++mi)
            af[mi] = *reinterpret_cast<const half8*>(&A0[(kit << 8) + (mi << 6) + lane]);
        #pragma unroll
        for (int ni = 0; ni < 4; ++ni)
            bf[ni] = *reinterpret_cast<const half8*>(&B0[(ni << 9) + (kit << 6)]);
        #pragma unroll
        for (int mi = 0; mi < 4; ++mi)
            #pragma unroll
            for (int ni = 0; ni < 4; ++ni)
                acc[mi][ni] = __builtin_amdgcn_mfma_f32_16x16x32_f16(af[mi], bf[ni], acc[mi][ni], 0, 0, 0);
    }

    // ---- + b0, LN stats (R2-proven serial-shfl reduction; byte-frozen R11)
    float bias[4], gm[4], bt[4];
    #pragma unroll
    for (int ni = 0; ni < 4; ++ni) {
        int col = (w << 6) + ni * 16 + l15;
        bias[ni] = b0[col]; gm[ni] = gamma[col]; bt[ni] = beta[col];
    }
    #pragma unroll
    for (int mi = 0; mi < 4; ++mi) {
        #pragma unroll
        for (int r = 0; r < 4; ++r) {
            float s = 0.f, ss = 0.f;
            #pragma unroll
            for (int ni = 0; ni < 4; ++ni) {
                float v = acc[mi][ni][r] + bias[ni];
                acc[mi][ni][r] = v;
                s += v; ss += v * v;
            }
            #pragma unroll
            for (int off = 1; off < 16; off <<= 1) {
                s  += __shfl_xor(s,  off, 64);
                ss += __shfl_xor(ss, off, 64);
            }
            if (l15 == 0) {
                int row = mi * 16 + q * 4 + r;
                psum[row][w] = s;
                psq[row][w]  = ss;
            }
        }
    }
    __syncthreads();    // also orders all A-loads before the in-place stores
    if (tid < 64) {
        float s  = psum[tid][0] + psum[tid][1] + psum[tid][2] + psum[tid][3];
        float ss = psq[tid][0]  + psq[tid][1]  + psq[tid][2]  + psq[tid][3];
        float mu = s * (1.f / 256.f);
        float var = ss * (1.f / 256.f) - mu * mu;
        mu_s[tid] = mu;
        rs_s[tid] = rsqrtf(var + 1e-5f);
    }
    __syncthreads();

    // ---- normalize + leaky + store fp16 (byte-frozen R11 epilogue)
    #pragma unroll
    for (int mi = 0; mi < 4; ++mi) {
        #pragma unroll
        for (int r = 0; r < 4; ++r) {
            int row = mi * 16 + q * 4 + r;
            float mu = mu_s[row], rs = rs_s[row];
            short* dst = H + (size_t)(m0 + row) * HID + (w << 6) + l15;
            #pragma unroll
            for (int ni = 0; ni < 4; ++ni) {
                float v = (acc[mi][ni][r] - mu) * rs * gm[ni] + bt[ni];
                v = (v >= 0.f) ? v : 0.1f * v;
                dst[ni * 16] = f2h(v);
            }
        }
    }
}

// ---------------------------------------------------------------------------
// K2: per (goal g, 64-row tile): t = relu(h @ W1[g] + b1[g]); out = t @ W2[g] + b2[g]
// H aliases out row-in-place (R2-proven race-free). R11-proven; untouched.
// ---------------------------------------------------------------------------
__global__ __launch_bounds__(256, 2) void k2_heads(
        const short* H, const short* __restrict__ W1F, const short* __restrict__ W2F,
        const float* __restrict__ b1, const float* __restrict__ b2,
        const int* __restrict__ cursor, const int* __restrict__ perm,
        float* out) {
    const int g = blockIdx.y;
    const int t = blockIdx.x;
    const int cnt = cursor[g];
    if (t * 64 >= cnt) return;

    __shared__ __align__(16) short a_lds[64][264];
    __shared__ __align__(16) short t_lds[64][136];
    __shared__ int rows_s[64];

    const int tid = threadIdx.x;
    const int lane = tid & 63;
    const int w = tid >> 6;
    const int* pg = perm + (size_t)g * BATCH;

    if (tid < 64) {
        int idx = t * 64 + tid;
        rows_s[tid] = pg[idx < cnt ? idx : cnt - 1];
    }
    __syncthreads();

    // ---- gather h rows (fp16), coalesced 16B/lane
    #pragma unroll
    for (int c = 0; c < 8; ++c) {
        int s = c * 256 + tid;                 // 16B slot, 64 rows x 32 slots
        int row = s >> 5;
        int k8 = (s & 31) << 3;
        short8 v = *reinterpret_cast<const short8*>(H + (size_t)rows_s[row] * HID + k8);
        *reinterpret_cast<short8*>(&a_lds[row][k8]) = v;
    }
    __syncthreads();

    const int q = lane >> 4;
    const int l15 = lane & 15;

    // ---- GEMM1: 64x128, K=256; wave w owns cols [w*32, w*32+32)
    floatx4 acc1[4][2] = {};
    const short8* B1 = reinterpret_cast<const short8*>(W1F) + (g << 12) + (w << 10) + lane;
    #pragma unroll
    for (int kit = 0; kit < 8; ++kit) {
        half8 af[4], bf[2];
        #pragma unroll
        for (int mi = 0; mi < 4; ++mi)
            af[mi] = *reinterpret_cast<const half8*>(&a_lds[mi * 16 + l15][kit * 32 + q * 8]);
        #pragma unroll
        for (int ni = 0; ni < 2; ++ni)
            bf[ni] = *reinterpret_cast<const half8*>(&B1[(ni << 9) + (kit << 6)]);
        #pragma unroll
        for (int mi = 0; mi < 4; ++mi)
            #pragma unroll
            for (int ni = 0; ni < 2; ++ni)
                acc1[mi][ni] = __builtin_amdgcn_mfma_f32_16x16x32_f16(af[mi], bf[ni], acc1[mi][ni], 0, 0, 0);
    }
    // bias + relu -> t_lds (fp16)
    #pragma unroll
    for (int ni = 0; ni < 2; ++ni) {
        int col = (w << 5) + ni * 16 + l15;
        float bb = b1[g * HHID + col];
        #pragma unroll
        for (int mi = 0; mi < 4; ++mi)
            #pragma unroll
            for (int r = 0; r < 4; ++r) {
                int row = mi * 16 + q * 4 + r;
                float v = acc1[mi][ni][r] + bb;
                t_lds[row][col] = f2h(v > 0.f ? v : 0.f);
            }
    }
    __syncthreads();

    // ---- GEMM2: 64x128, K=128
    floatx4 acc2[4][2] = {};
    const short8* B2 = reinterpret_cast<const short8*>(W2F) + (g << 11) + (w << 9) + lane;
    #pragma unroll
    for (int kit = 0; kit < 4; ++kit) {
        half8 af[4], bf[2];
        #pragma unroll
        for (int mi = 0; mi < 4; ++mi)
            af[mi] = *reinterpret_cast<const half8*>(&t_lds[mi * 16 + l15][kit * 32 + q * 8]);
        #pragma unroll
        for (int ni = 0; ni < 2; ++ni)
            bf[ni] = *reinterpret_cast<const half8*>(&B2[(ni << 8) + (kit << 6)]);
        #pragma unroll
        for (int mi = 0; mi < 4; ++mi)
            #pragma unroll
            for (int ni = 0; ni < 2; ++ni)
                acc2[mi][ni] = __builtin_amdgcn_mfma_f32_16x16x32_f16(af[mi], bf[ni], acc2[mi][ni], 0, 0, 0);
    }
    // bias + scatter out (fp32)
    #pragma unroll
    for (int ni = 0; ni < 2; ++ni) {
        int col = (w << 5) + ni * 16 + l15;
        float bb = b2[g * ODIM + col];
        #pragma unroll
        for (int mi = 0; mi < 4; ++mi)
            #pragma unroll
            for (int r = 0; r < 4; ++r) {
                int row = mi * 16 + q * 4 + r;
                int idx = t * 64 + row;
                if (idx < cnt)
                    out[(size_t)rows_s[row] * ODIM + col] = acc2[mi][ni][r] + bb;
            }
    }
}

// ---------------------------------------------------------------------------
// workspace layout (2.62 MB):
//   [0, 131072)            W0F fp16 (fragment-ordered)
//   [131072, 393216)       W1F fp16
//   [393216, 524288)       W2F fp16
//   [524288, 524304)       cursor (padded to 1024)
//   [525312, 2622464)      perm (4 x 131072 int)
// d_out pipeline (tile-in-place at every step, one owner block per tile):
//   xcvt: x -> XB (fp16, A-fragment order) | k1d: XB tile -> H rows (same
//   32KB, row-major) | k2: H -> out (fp32, row-in-place)
// ---------------------------------------------------------------------------
extern "C" void kernel_launch(void* const* d_in, const int* in_sizes, int n_in,
                              void* d_out, int out_size, void* d_ws, size_t ws_size,
                              hipStream_t stream) {
    const float* x     = (const float*)d_in[0];
    const float* W0    = (const float*)d_in[1];
    const float* b0    = (const float*)d_in[2];
    const float* gamma = (const float*)d_in[3];
    const float* beta  = (const float*)d_in[4];
    const float* W1    = (const float*)d_in[5];
    const float* b1    = (const float*)d_in[6];
    const float* W2    = (const float*)d_in[7];
    const float* b2    = (const float*)d_in[8];

    char* ws = (char*)d_ws;
    short* W0F  = (short*)(ws);
    short* W1F  = (short*)(ws + 131072);
    short* W2F  = (short*)(ws + 393216);
    int* cursor = (int*)(ws + 524288);
    int* perm   = (int*)(ws + 525312);
    short* XB   = (short*)d_out;           // fp16 frag-A, then h, then fp32 out
    float* out  = (float*)d_out;

    prep_kernel<<<512, 256, 0, stream>>>(W0, W1, W2, W0F, W1F, W2F, cursor);
    bucket_kernel<<<512, 256, 0, stream>>>(x, cursor, perm);
    xcvt_kernel<<<BATCH / 64, 256, 0, stream>>>(x, XB);
    k1d_gemm_ln<<<BATCH / 64, 256, 0, stream>>>(XB, b0, gamma, beta, W0F, XB);
    k2_heads<<<dim3(BATCH / 64, 4), 256, 0, stream>>>(XB, W1F, W2F, b1, b2, cursor, perm, out);
}

// Round 16
// 111.114 us; speedup vs baseline: 1.4887x; 1.2159x over previous
//
#include <hip/hip_runtime.h>

#define BATCH 131072
#define XDIM 260          // 256 state + 4 goal
#define SDIM 256
#define HID 256
#define HHID 128
#define ODIM 128

typedef __attribute__((ext_vector_type(8))) short short8;     // raw 16B moves
typedef __attribute__((ext_vector_type(4))) short short4v;
typedef __attribute__((ext_vector_type(4))) float floatx4;    // MFMA accum
typedef __attribute__((ext_vector_type(8))) _Float16 half8;   // f16 MFMA frag

// fp32 -> fp16 RTNE. R11-proven absmax 9.77e-4 vs 4.22e-3 threshold.
__device__ __forceinline__ short f2h(float f) {
    union { _Float16 h; short s; } u;
    u.h = (_Float16)f;
    return u.s;
}

// ---------------------------------------------------------------------------
// prep: weights -> fp16 in MFMA-fragment order (R11-proven).
//   W0F[c:16][kit:8][lane:64][e:8]   W1F[g][c:8][kit:8][lane][e]
//   W2F[g][c:8][kit:4][lane][e]
// frag value for lane (q=lane>>4, l15=lane&15), elem e:
//   W[k = kit*32 + q*8 + e][col = c*16 + l15]
// ---------------------------------------------------------------------------
__global__ void prep_kernel(const float* __restrict__ W0, const float* __restrict__ W1,
                            const float* __restrict__ W2, short* __restrict__ W0F,
                            short* __restrict__ W1F, short* __restrict__ W2F,
                            int* __restrict__ cursor) {
    int i = blockIdx.x * 256 + threadIdx.x;   // grid 512*256 = 131072
    if (i < 4) cursor[i] = 0;
    if (i < 65536) {            // W0F
        int e = i & 7, lane = (i >> 3) & 63, kit = (i >> 9) & 7, c = (i >> 12) & 15;
        int col = c * 16 + (lane & 15);
        int k = kit * 32 + (lane >> 4) * 8 + e;
        W0F[i] = f2h(W0[k * HID + col]);
    }
    {                           // W1F (exactly 131072 elements)
        int e = i & 7, lane = (i >> 3) & 63, kit = (i >> 9) & 7, c = (i >> 12) & 7, g = i >> 15;
        int col = c * 16 + (lane & 15);
        int k = kit * 32 + (lane >> 4) * 8 + e;
        W1F[i] = f2h(W1[(g * SDIM + k) * HHID + col]);
    }
    if (i < 65536) {            // W2F
        int e = i & 7, lane = (i >> 3) & 63, kit = (i >> 9) & 3, c = (i >> 11) & 7, g = i >> 14;
        int col = c * 16 + (lane & 15);
        int k = kit * 32 + (lane >> 4) * 8 + e;
        W2F[i] = f2h(W2[(g * HHID + k) * ODIM + col]);
    }
}

// ---------------------------------------------------------------------------
// bucket: per-row argmax(goal) -> counting sort (hierarchical; R2-proven).
// ---------------------------------------------------------------------------
__global__ void bucket_kernel(const float* __restrict__ x, int* __restrict__ cursor,
                              int* __restrict__ perm) {
    __shared__ int lhist[4];
    __shared__ int lbase[4];
    const int tid = threadIdx.x;
    if (tid < 4) lhist[tid] = 0;
    __syncthreads();

    const int row = blockIdx.x * 256 + tid;
    const float4 gv = *reinterpret_cast<const float4*>(x + (size_t)row * XDIM + SDIM);
    int gi = 0; float best = gv.x;
    if (gv.y > best) { best = gv.y; gi = 1; }   // strict > keeps first max (jnp.argmax)
    if (gv.z > best) { best = gv.z; gi = 2; }
    if (gv.w > best) { best = gv.w; gi = 3; }

    const int lpos = atomicAdd(&lhist[gi], 1);
    __syncthreads();
    if (tid < 4) lbase[tid] = atomicAdd(&cursor[tid], lhist[tid]);
    __syncthreads();
    perm[gi * BATCH + lbase[gi] + lpos] = row;
}

// ---------------------------------------------------------------------------
// K1: h = LeakyReLU(LN(state @ W0 + b0)) -> fp16 H (aliases d_out, in place).
// R11 exactly: 64-row tile, 256 threads, 4 waves; sched_barrier-batched
// fp32 staging; fragment-ordered B loads (contiguous 1KB/wave);
// serial-shfl LN; scalar-store epilogue. Passed post-timing 5x (R9-R13).
// ---------------------------------------------------------------------------
__global__ __launch_bounds__(256, 4) void k1_gemm_ln(
        const float* __restrict__ x, const float* __restrict__ b0,
        const float* __restrict__ gamma, const float* __restrict__ beta,
        const short* __restrict__ W0F, short* __restrict__ H) {
    __shared__ __align__(16) short a_lds[64][264];   // 256 + 8 pad
    __shared__ float psum[64][4];
    __shared__ float psq[64][4];
    __shared__ float mu_s[64];
    __shared__ float rs_s[64];

    const int tid = threadIdx.x;
    const int lane = tid & 63;
    const int w = tid >> 6;
    const int m0 = blockIdx.x * 64;

    // ---- stage x(state) fp32 -> fp16 LDS; 2 batches of 8 in-flight float4s
    #pragma unroll
    for (int half = 0; half < 2; ++half) {
        float4 v[8];
        #pragma unroll
        for (int c = 0; c < 8; ++c) {
            int s = (half * 8 + c) * 256 + tid;     // float4 slot, 64 rows x 64 slots
            int row = s >> 6;
            int k4 = (s & 63) << 2;
            v[c] = *reinterpret_cast<const float4*>(x + (size_t)(m0 + row) * XDIM + k4);
        }
        __builtin_amdgcn_sched_barrier(0);   // keep all 8 loads issued before any use
        #pragma unroll
        for (int c = 0; c < 8; ++c) {
            int s = (half * 8 + c) * 256 + tid;
            int row = s >> 6;
            int k4 = (s & 63) << 2;
            short4v sv;
            sv.x = f2h(v[c].x); sv.y = f2h(v[c].y); sv.z = f2h(v[c].z); sv.w = f2h(v[c].w);
            *reinterpret_cast<short4v*>(&a_lds[row][k4]) = sv;
        }
    }
    __syncthreads();

    const int q = lane >> 4;
    const int l15 = lane & 15;

    floatx4 acc[4][4] = {};                    // [mi][ni], rows mi*16+q*4+r, cols w*64+ni*16+l15
    const short8* B0 = reinterpret_cast<const short8*>(W0F) + (w << 11) + lane;

    #pragma unroll
    for (int kit = 0; kit < 8; ++kit) {
        half8 af[4], bf[4];
        #pragma unroll
        for (int mi = 0; mi < 4; ++mi)
            af[mi] = *reinterpret_cast<const half8*>(&a_lds[mi * 16 + l15][kit * 32 + q * 8]);
        #pragma unroll
        for (int ni = 0; ni < 4; ++ni)
            bf[ni] = *reinterpret_cast<const half8*>(&B0[(ni << 9) + (kit << 6)]);
        #pragma unroll
        for (int mi = 0; mi < 4; ++mi)
            #pragma unroll
            for (int ni = 0; ni < 4; ++ni)
                acc[mi][ni] = __builtin_amdgcn_mfma_f32_16x16x32_f16(af[mi], bf[ni], acc[mi][ni], 0, 0, 0);
    }

    // ---- + b0, LN stats (R2-proven serial-shfl reduction)
    float bias[4], gm[4], bt[4];
    #pragma unroll
    for (int ni = 0; ni < 4; ++ni) {
        int col = (w << 6) + ni * 16 + l15;
        bias[ni] = b0[col]; gm[ni] = gamma[col]; bt[ni] = beta[col];
    }
    #pragma unroll
    for (int mi = 0; mi < 4; ++mi) {
        #pragma unroll
        for (int r = 0; r < 4; ++r) {
            float s = 0.f, ss = 0.f;
            #pragma unroll
            for (int ni = 0; ni < 4; ++ni) {
                float v = acc[mi][ni][r] + bias[ni];
                acc[mi][ni][r] = v;
                s += v; ss += v * v;
            }
            #pragma unroll
            for (int off = 1; off < 16; off <<= 1) {
                s  += __shfl_xor(s,  off, 64);
                ss += __shfl_xor(ss, off, 64);
            }
            if (l15 == 0) {
                int row = mi * 16 + q * 4 + r;
                psum[row][w] = s;
                psq[row][w]  = ss;
            }
        }
    }
    __syncthreads();
    if (tid < 64) {
        float s  = psum[tid][0] + psum[tid][1] + psum[tid][2] + psum[tid][3];
        float ss = psq[tid][0]  + psq[tid][1]  + psq[tid][2]  + psq[tid][3];
        float mu = s * (1.f / 256.f);
        float var = ss * (1.f / 256.f) - mu * mu;
        mu_s[tid] = mu;
        rs_s[tid] = rsqrtf(var + 1e-5f);
    }
    __syncthreads();

    // ---- normalize + leaky + store fp16 (R2-proven scalar store epilogue)
    #pragma unroll
    for (int mi = 0; mi < 4; ++mi) {
        #pragma unroll
        for (int r = 0; r < 4; ++r) {
            int row = mi * 16 + q * 4 + r;
            float mu = mu_s[row], rs = rs_s[row];
            short* dst = H + (size_t)(m0 + row) * HID + (w << 6) + l15;
            #pragma unroll
            for (int ni = 0; ni < 4; ++ni) {
                float v = (acc[mi][ni][r] - mu) * rs * gm[ni] + bt[ni];
                v = (v >= 0.f) ? v : 0.1f * v;
                dst[ni * 16] = f2h(v);
            }
        }
    }
}

// ---------------------------------------------------------------------------
// K2: per (goal g, 64-row tile): t = relu(h @ W1[g] + b1[g]); out = t @ W2[g] + b2[g]
// H aliases out row-in-place (R2-proven race-free). R11-proven; untouched.
// ---------------------------------------------------------------------------
__global__ __launch_bounds__(256, 2) void k2_heads(
        const short* H, const short* __restrict__ W1F, const short* __restrict__ W2F,
        const float* __restrict__ b1, const float* __restrict__ b2,
        const int* __restrict__ cursor, const int* __restrict__ perm,
        float* out) {
    const int g = blockIdx.y;
    const int t = blockIdx.x;
    const int cnt = cursor[g];
    if (t * 64 >= cnt) return;

    __shared__ __align__(16) short a_lds[64][264];
    __shared__ __align__(16) short t_lds[64][136];
    __shared__ int rows_s[64];

    const int tid = threadIdx.x;
    const int lane = tid & 63;
    const int w = tid >> 6;
    const int* pg = perm + (size_t)g * BATCH;

    if (tid < 64) {
        int idx = t * 64 + tid;
        rows_s[tid] = pg[idx < cnt ? idx : cnt - 1];
    }
    __syncthreads();

    // ---- gather h rows (fp16), coalesced 16B/lane
    #pragma unroll
    for (int c = 0; c < 8; ++c) {
        int s = c * 256 + tid;                 // 16B slot, 64 rows x 32 slots
        int row = s >> 5;
        int k8 = (s & 31) << 3;
        short8 v = *reinterpret_cast<const short8*>(H + (size_t)rows_s[row] * HID + k8);
        *reinterpret_cast<short8*>(&a_lds[row][k8]) = v;
    }
    __syncthreads();

    const int q = lane >> 4;
    const int l15 = lane & 15;

    // ---- GEMM1: 64x128, K=256; wave w owns cols [w*32, w*32+32)
    floatx4 acc1[4][2] = {};
    const short8* B1 = reinterpret_cast<const short8*>(W1F) + (g << 12) + (w << 10) + lane;
    #pragma unroll
    for (int kit = 0; kit < 8; ++kit) {
        half8 af[4], bf[2];
        #pragma unroll
        for (int mi = 0; mi < 4; ++mi)
            af[mi] = *reinterpret_cast<const half8*>(&a_lds[mi * 16 + l15][kit * 32 + q * 8]);
        #pragma unroll
        for (int ni = 0; ni < 2; ++ni)
            bf[ni] = *reinterpret_cast<const half8*>(&B1[(ni << 9) + (kit << 6)]);
        #pragma unroll
        for (int mi = 0; mi < 4; ++mi)
            #pragma unroll
            for (int ni = 0; ni < 2; ++ni)
                acc1[mi][ni] = __builtin_amdgcn_mfma_f32_16x16x32_f16(af[mi], bf[ni], acc1[mi][ni], 0, 0, 0);
    }
    // bias + relu -> t_lds (fp16)
    #pragma unroll
    for (int ni = 0; ni < 2; ++ni) {
        int col = (w << 5) + ni * 16 + l15;
        float bb = b1[g * HHID + col];
        #pragma unroll
        for (int mi = 0; mi < 4; ++mi)
            #pragma unroll
            for (int r = 0; r < 4; ++r) {
                int row = mi * 16 + q * 4 + r;
                float v = acc1[mi][ni][r] + bb;
                t_lds[row][col] = f2h(v > 0.f ? v : 0.f);
            }
    }
    __syncthreads();

    // ---- GEMM2: 64x128, K=128
    floatx4 acc2[4][2] = {};
    const short8* B2 = reinterpret_cast<const short8*>(W2F) + (g << 11) + (w << 9) + lane;
    #pragma unroll
    for (int kit = 0; kit < 4; ++kit) {
        half8 af[4], bf[2];
        #pragma unroll
        for (int mi = 0; mi < 4; ++mi)
            af[mi] = *reinterpret_cast<const half8*>(&t_lds[mi * 16 + l15][kit * 32 + q * 8]);
        #pragma unroll
        for (int ni = 0; ni < 2; ++ni)
            bf[ni] = *reinterpret_cast<const half8*>(&B2[(ni << 8) + (kit << 6)]);
        #pragma unroll
        for (int mi = 0; mi < 4; ++mi)
            #pragma unroll
            for (int ni = 0; ni < 2; ++ni)
                acc2[mi][ni] = __builtin_amdgcn_mfma_f32_16x16x32_f16(af[mi], bf[ni], acc2[mi][ni], 0, 0, 0);
    }
    // bias + scatter out (fp32)
    #pragma unroll
    for (int ni = 0; ni < 2; ++ni) {
        int col = (w << 5) + ni * 16 + l15;
        float bb = b2[g * ODIM + col];
        #pragma unroll
        for (int mi = 0; mi < 4; ++mi)
            #pragma unroll
            for (int r = 0; r < 4; ++r) {
                int row = mi * 16 + q * 4 + r;
                int idx = t * 64 + row;
                if (idx < cnt)
                    out[(size_t)rows_s[row] * ODIM + col] = acc2[mi][ni][r] + bb;
            }
    }
}

// ---------------------------------------------------------------------------
// workspace layout (2.62 MB):
//   [0, 131072)            W0F fp16 (fragment-ordered)
//   [131072, 393216)       W1F fp16
//   [393216, 524288)       W2F fp16
//   [524288, 524304)       cursor (padded to 1024)
//   [525312, 2622464)      perm (4 x 131072 int)
// h (fp16, 64 MB) lives in d_out (row-in-place; one owner block per row).
// ---------------------------------------------------------------------------
extern "C" void kernel_launch(void* const* d_in, const int* in_sizes, int n_in,
                              void* d_out, int out_size, void* d_ws, size_t ws_size,
                              hipStream_t stream) {
    const float* x     = (const float*)d_in[0];
    const float* W0    = (const float*)d_in[1];
    const float* b0    = (const float*)d_in[2];
    const float* gamma = (const float*)d_in[3];
    const float* beta  = (const float*)d_in[4];
    const float* W1    = (const float*)d_in[5];
    const float* b1    = (const float*)d_in[6];
    const float* W2    = (const float*)d_in[7];
    const float* b2    = (const float*)d_in[8];

    char* ws = (char*)d_ws;
    short* W0F  = (short*)(ws);
    short* W1F  = (short*)(ws + 131072);
    short* W2F  = (short*)(ws + 393216);
    int* cursor = (int*)(ws + 524288);
    int* perm   = (int*)(ws + 525312);
    short* H    = (short*)d_out;           // fp16 h aliases the fp32 output buffer
    float* out  = (float*)d_out;

    prep_kernel<<<512, 256, 0, stream>>>(W0, W1, W2, W0F, W1F, W2F, cursor);
    bucket_kernel<<<512, 256, 0, stream>>>(x, cursor, perm);
    k1_gemm_ln<<<BATCH / 64, 256, 0, stream>>>(x, b0, gamma, beta, W0F, H);
    k2_heads<<<dim3(BATCH / 64, 4), 256, 0, stream>>>(H, W1F, W2F, b1, b2, cursor, perm, out);
}